// Round 1
// baseline (3728.877 us; speedup 1.0000x reference)
//
#include <hip/hip_runtime.h>
#include <hip/hip_bf16.h>
#include <math.h>

// Problem constants
#define S_LEN 1024
#define HDIM  2880
#define NH    64
#define NKV   8
#define HD    64
#define QKV_N ((NH + 2*NKV) * HD)   // 5120
#define O_K   (NH * HD)             // 4096
#define SCALE 0.125f                // HD^-0.5

// ---------------------------------------------------------------------------
// GEMM: C[M,N] = A[M,K] * B[N,K]^T   (both row-major, K contiguous)
// 64x64 tile, 16 K-slab, 256 threads, 4x4 register micro-tile per thread.
// ---------------------------------------------------------------------------
#define TS 64
#define KS 16

__global__ __launch_bounds__(256) void gemm_bt_f32(const float* __restrict__ A,
                                                   const float* __restrict__ B,
                                                   float* __restrict__ C,
                                                   int M, int N, int K) {
    __shared__ float As[KS][TS + 1];
    __shared__ float Bs[KS][TS + 1];
    const int tid = threadIdx.x;
    const int tx = tid & 15;        // 0..15  -> col group (4 cols)
    const int ty = tid >> 4;        // 0..15  -> row group (4 rows)
    const int row0 = blockIdx.y * TS;
    const int col0 = blockIdx.x * TS;

    // loader mapping: thread loads one float4 of A-tile and one of B-tile
    const int lr = tid >> 2;              // 0..63 tile row
    const int lc = (tid & 3) << 2;        // 0,4,8,12 k offset

    float acc[4][4] = {};

    for (int k0 = 0; k0 < K; k0 += KS) {
        const float4 av = *(const float4*)&A[(size_t)(row0 + lr) * K + k0 + lc];
        const float4 bv = *(const float4*)&B[(size_t)(col0 + lr) * K + k0 + lc];
        As[lc + 0][lr] = av.x; As[lc + 1][lr] = av.y;
        As[lc + 2][lr] = av.z; As[lc + 3][lr] = av.w;
        Bs[lc + 0][lr] = bv.x; Bs[lc + 1][lr] = bv.y;
        Bs[lc + 2][lr] = bv.z; Bs[lc + 3][lr] = bv.w;
        __syncthreads();
#pragma unroll
        for (int kk = 0; kk < KS; ++kk) {
            float a[4], b[4];
#pragma unroll
            for (int i = 0; i < 4; ++i) a[i] = As[kk][ty * 4 + i];
#pragma unroll
            for (int j = 0; j < 4; ++j) b[j] = Bs[kk][tx * 4 + j];
#pragma unroll
            for (int i = 0; i < 4; ++i)
#pragma unroll
                for (int j = 0; j < 4; ++j) acc[i][j] = fmaf(a[i], b[j], acc[i][j]);
        }
        __syncthreads();
    }

#pragma unroll
    for (int i = 0; i < 4; ++i) {
        const int r = row0 + ty * 4 + i;
        float4 v = make_float4(acc[i][0], acc[i][1], acc[i][2], acc[i][3]);
        *(float4*)&C[(size_t)r * N + col0 + tx * 4] = v;
    }
}

// ---------------------------------------------------------------------------
// RoPE applied in-place to q (heads 0..63) and k (heads 64..71) slices of qkv.
// one block per sequence position.
// ---------------------------------------------------------------------------
__global__ __launch_bounds__(256) void rope_kernel(float* __restrict__ qkv,
                                                   const int* __restrict__ positions) {
    const int s = blockIdx.x;
    const float pos = (float)positions[s];
    float* row = qkv + (size_t)s * QKV_N;
    // 72 roped heads (64 q + 8 k) x 32 rotation pairs
    for (int w = threadIdx.x; w < 72 * 32; w += 256) {
        const int h = w >> 5;
        const int t = w & 31;
        // inv_freq = 10000^(-t/32) = exp2(-t/32 * log2(10000))
        const float inv_freq = exp2f(-(float)t * (13.287712379549449f / 32.0f));
        const float ang = pos * inv_freq;
        float sn, cs;
        sincosf(ang, &sn, &cs);   // precise version: large-angle range reduction
        float* base = row + h * HD;
        const float x1 = base[t];
        const float x2 = base[t + 32];
        base[t]      = x1 * cs - x2 * sn;
        base[t + 32] = x2 * cs + x1 * sn;
    }
}

// ---------------------------------------------------------------------------
// Attention: one wave (64 threads) per (head n, query row qi).
// Online softmax initialized with the sink: m=sink, l=1 (exp(sink-m)), o=0.
// Lane t owns dimension t of q and of the output.
// ---------------------------------------------------------------------------
__global__ __launch_bounds__(64) void attn_kernel(const float* __restrict__ qkv,
                                                  const float* __restrict__ sinks,
                                                  const int* __restrict__ positions,
                                                  float* __restrict__ attn_out) {
    __shared__ int pos_s[S_LEN];
    const int n  = blockIdx.x;   // query head
    const int qi = blockIdx.y;   // query row
    const int t  = threadIdx.x;  // 0..63 = dim

    for (int i = t; i < S_LEN; i += 64) pos_s[i] = positions[i];
    __syncthreads();

    const int g = n >> 3;        // kv head = n / G, G = 8
    const float qv = qkv[(size_t)qi * QKV_N + n * HD + t];
    const int mypos = pos_s[qi];

    float m = sinks[n];
    float l = 1.0f;
    float o = 0.0f;

    for (int k = 0; k < S_LEN; ++k) {
        if (pos_s[k] > mypos) continue;   // wave-uniform branch
        const float* krow = qkv + (size_t)k * QKV_N + NH * HD + g * HD;
        const float kd = krow[t];
        const float vd = krow[t + NKV * HD];   // v lives 512 floats after k
        float dot = qv * kd;
#pragma unroll
        for (int off = 32; off > 0; off >>= 1) dot += __shfl_xor(dot, off, 64);
        const float sc = dot * SCALE;
        const float nm = fmaxf(m, sc);
        const float alpha = __expf(m - nm);
        const float p = __expf(sc - nm);
        l = l * alpha + p;
        o = o * alpha + p * vd;
        m = nm;
    }
    attn_out[(size_t)qi * O_K + n * HD + t] = o / l;
}

// ---------------------------------------------------------------------------
extern "C" void kernel_launch(void* const* d_in, const int* in_sizes, int n_in,
                              void* d_out, int out_size, void* d_ws, size_t ws_size,
                              hipStream_t stream) {
    const int*   positions = (const int*)d_in[0];
    const float* hidden    = (const float*)d_in[1];   // (1024, 2880)
    const float* qkv_w     = (const float*)d_in[2];   // (5120, 2880)
    const float* o_w       = (const float*)d_in[3];   // (2880, 4096)
    const float* sinks     = (const float*)d_in[4];   // (64,)
    float* out = (float*)d_out;                       // (1024, 2880)

    float* qkv  = (float*)d_ws;                       // 1024*5120 f32 = 20 MB
    float* attn = qkv + (size_t)S_LEN * QKV_N;        // 1024*4096 f32 = 16 MB

    // 1) qkv = hidden @ qkv_w.T   (M=1024, N=5120, K=2880)
    gemm_bt_f32<<<dim3(QKV_N / TS, S_LEN / TS), 256, 0, stream>>>(
        hidden, qkv_w, qkv, S_LEN, QKV_N, HDIM);

    // 2) RoPE in place on q,k
    rope_kernel<<<S_LEN, 256, 0, stream>>>(qkv, positions);

    // 3) attention -> attn (1024, 4096)
    attn_kernel<<<dim3(NH, S_LEN), 64, 0, stream>>>(qkv, sinks, positions, attn);

    // 4) out = attn @ o_w.T   (M=1024, N=2880, K=4096)
    gemm_bt_f32<<<dim3(HDIM / TS, S_LEN / TS), 256, 0, stream>>>(
        attn, o_w, out, S_LEN, HDIM, O_K);
}

// Round 2
// 1359.903 us; speedup vs baseline: 2.7420x; 2.7420x over previous
//
#include <hip/hip_runtime.h>
#include <hip/hip_bf16.h>
#include <math.h>

// Problem constants
#define S_LEN 1024
#define HDIM  2880
#define NH    64
#define NKV   8
#define HD    64
#define QKV_N ((NH + 2*NKV) * HD)   // 5120
#define O_K   (NH * HD)             // 4096
#define SCALE 0.125f                // HD^-0.5

// ---------------------------------------------------------------------------
// GEMM: C[M,N] = A[M,K] * B[N,K]^T   (both row-major, K contiguous)
// 64x64 tile, 16 K-slab, 256 threads, 4x4 register micro-tile per thread.
// ---------------------------------------------------------------------------
#define TS 64
#define KS 16

__global__ __launch_bounds__(256) void gemm_bt_f32(const float* __restrict__ A,
                                                   const float* __restrict__ B,
                                                   float* __restrict__ C,
                                                   int M, int N, int K) {
    __shared__ float As[KS][TS + 1];
    __shared__ float Bs[KS][TS + 1];
    const int tid = threadIdx.x;
    const int tx = tid & 15;        // 0..15  -> col group (4 cols)
    const int ty = tid >> 4;        // 0..15  -> row group (4 rows)
    const int row0 = blockIdx.y * TS;
    const int col0 = blockIdx.x * TS;

    const int lr = tid >> 2;              // 0..63 tile row
    const int lc = (tid & 3) << 2;        // 0,4,8,12 k offset

    float acc[4][4] = {};

    for (int k0 = 0; k0 < K; k0 += KS) {
        const float4 av = *(const float4*)&A[(size_t)(row0 + lr) * K + k0 + lc];
        const float4 bv = *(const float4*)&B[(size_t)(col0 + lr) * K + k0 + lc];
        As[lc + 0][lr] = av.x; As[lc + 1][lr] = av.y;
        As[lc + 2][lr] = av.z; As[lc + 3][lr] = av.w;
        Bs[lc + 0][lr] = bv.x; Bs[lc + 1][lr] = bv.y;
        Bs[lc + 2][lr] = bv.z; Bs[lc + 3][lr] = bv.w;
        __syncthreads();
#pragma unroll
        for (int kk = 0; kk < KS; ++kk) {
            float a[4], b[4];
#pragma unroll
            for (int i = 0; i < 4; ++i) a[i] = As[kk][ty * 4 + i];
#pragma unroll
            for (int j = 0; j < 4; ++j) b[j] = Bs[kk][tx * 4 + j];
#pragma unroll
            for (int i = 0; i < 4; ++i)
#pragma unroll
                for (int j = 0; j < 4; ++j) acc[i][j] = fmaf(a[i], b[j], acc[i][j]);
        }
        __syncthreads();
    }

#pragma unroll
    for (int i = 0; i < 4; ++i) {
        const int r = row0 + ty * 4 + i;
        float4 v = make_float4(acc[i][0], acc[i][1], acc[i][2], acc[i][3]);
        *(float4*)&C[(size_t)r * N + col0 + tx * 4] = v;
    }
}

// ---------------------------------------------------------------------------
// RoPE applied in-place to q (heads 0..63) and k (heads 64..71) slices of qkv.
// ---------------------------------------------------------------------------
__global__ __launch_bounds__(256) void rope_kernel(float* __restrict__ qkv,
                                                   const int* __restrict__ positions) {
    const int s = blockIdx.x;
    const float pos = (float)positions[s];
    float* row = qkv + (size_t)s * QKV_N;
    for (int w = threadIdx.x; w < 72 * 32; w += 256) {
        const int h = w >> 5;
        const int t = w & 31;
        const float inv_freq = exp2f(-(float)t * (13.287712379549449f / 32.0f));
        const float ang = pos * inv_freq;
        float sn, cs;
        sincosf(ang, &sn, &cs);
        float* base = row + h * HD;
        const float x1 = base[t];
        const float x2 = base[t + 32];
        base[t]      = x1 * cs - x2 * sn;
        base[t + 32] = x2 * cs + x1 * sn;
    }
}

// ---------------------------------------------------------------------------
// Flash-style attention. One workgroup (256 thr) per (head n, 64-query tile).
// Thread (ty,tx) owns 4x4 micro-tiles: rows q = ty*4+i, cols (keys or dims)
// tx*4+j. Online softmax with sink init (m=sink, l=1). Causal skip: q-tile qt
// only visits key tiles 0..qt; masking only on the diagonal tile.
// ---------------------------------------------------------------------------
__global__ __launch_bounds__(256) void attn_flash(const float* __restrict__ qkv,
                                                  const float* __restrict__ sinks,
                                                  const int* __restrict__ positions,
                                                  float* __restrict__ attn_out) {
    __shared__ float Qs[64][64];   // [d][q]   (transposed)
    __shared__ float KP[64][64];   // phase 1: K [d][k]; phase 2: P [q][k]
    __shared__ float Vs[64][64];   // [k][d]   (natural)
    __shared__ int   posk[64];

    const int tid = threadIdx.x;
    const int tx  = tid & 15;
    const int ty  = tid >> 4;
    const int n   = blockIdx.x;                       // query head
    const int qt  = (int)gridDim.y - 1 - (int)blockIdx.y;  // heavy tiles first
    const int g   = n >> 3;                           // kv head

    // ---- stage Q tile (once), transposed to [d][q] ----
    const float* Qg = qkv + (size_t)(qt * 64) * QKV_N + n * HD;
#pragma unroll
    for (int it = 0; it < 4; ++it) {
        const int flat = it * 256 + tid;
        const int r = flat >> 4, c4 = (flat & 15) * 4;
        const float4 v = *(const float4*)&Qg[(size_t)r * QKV_N + c4];
        Qs[c4 + 0][r] = v.x; Qs[c4 + 1][r] = v.y;
        Qs[c4 + 2][r] = v.z; Qs[c4 + 3][r] = v.w;
    }

    int pq[4];
#pragma unroll
    for (int i = 0; i < 4; ++i) pq[i] = positions[qt * 64 + ty * 4 + i];

    const float sinkv = sinks[n];
    float m[4], l[4], o[4][4];
#pragma unroll
    for (int i = 0; i < 4; ++i) {
        m[i] = sinkv; l[i] = 1.0f;
#pragma unroll
        for (int j = 0; j < 4; ++j) o[i][j] = 0.0f;
    }

    for (int kt = 0; kt <= qt; ++kt) {
        __syncthreads();   // prev PV reads done (iter0: nothing), Q stage pending
        // ---- stage K transposed [d][k], V natural [k][d] ----
        const float* Kg = qkv + (size_t)(kt * 64) * QKV_N + NH * HD + g * HD;
        const float* Vg = Kg + NKV * HD;
#pragma unroll
        for (int it = 0; it < 4; ++it) {
            const int flat = it * 256 + tid;
            const int r = flat >> 4, c4 = (flat & 15) * 4;
            const float4 kv = *(const float4*)&Kg[(size_t)r * QKV_N + c4];
            KP[c4 + 0][r] = kv.x; KP[c4 + 1][r] = kv.y;
            KP[c4 + 2][r] = kv.z; KP[c4 + 3][r] = kv.w;
            const float4 vv = *(const float4*)&Vg[(size_t)r * QKV_N + c4];
            *(float4*)&Vs[r][c4] = vv;
        }
        if (tid < 64) posk[tid] = positions[kt * 64 + tid];
        __syncthreads();

        // ---- S = Q K^T (4x4 per thread) ----
        float s[4][4] = {};
#pragma unroll 4
        for (int d = 0; d < 64; ++d) {
            const float4 qa = *(const float4*)&Qs[d][ty * 4];
            const float4 kb = *(const float4*)&KP[d][tx * 4];
            const float a0 = qa.x, a1 = qa.y, a2 = qa.z, a3 = qa.w;
            const float b0 = kb.x, b1 = kb.y, b2 = kb.z, b3 = kb.w;
            s[0][0] = fmaf(a0, b0, s[0][0]); s[0][1] = fmaf(a0, b1, s[0][1]);
            s[0][2] = fmaf(a0, b2, s[0][2]); s[0][3] = fmaf(a0, b3, s[0][3]);
            s[1][0] = fmaf(a1, b0, s[1][0]); s[1][1] = fmaf(a1, b1, s[1][1]);
            s[1][2] = fmaf(a1, b2, s[1][2]); s[1][3] = fmaf(a1, b3, s[1][3]);
            s[2][0] = fmaf(a2, b0, s[2][0]); s[2][1] = fmaf(a2, b1, s[2][1]);
            s[2][2] = fmaf(a2, b2, s[2][2]); s[2][3] = fmaf(a2, b3, s[2][3]);
            s[3][0] = fmaf(a3, b0, s[3][0]); s[3][1] = fmaf(a3, b1, s[3][1]);
            s[3][2] = fmaf(a3, b2, s[3][2]); s[3][3] = fmaf(a3, b3, s[3][3]);
        }

        // ---- scale + causal mask (diag tile only) ----
        const bool diag = (kt == qt);
        int pk[4];
        if (diag) {
#pragma unroll
            for (int j = 0; j < 4; ++j) pk[j] = posk[tx * 4 + j];
        }
#pragma unroll
        for (int i = 0; i < 4; ++i)
#pragma unroll
            for (int j = 0; j < 4; ++j) {
                float sv = s[i][j] * SCALE;
                if (diag && pk[j] > pq[i]) sv = -3.0e38f;
                s[i][j] = sv;
            }

        // ---- online softmax (row reduce over 16 tx lanes) ----
#pragma unroll
        for (int i = 0; i < 4; ++i) {
            float tm = fmaxf(fmaxf(s[i][0], s[i][1]), fmaxf(s[i][2], s[i][3]));
            tm = fmaxf(tm, __shfl_xor(tm, 1, 64));
            tm = fmaxf(tm, __shfl_xor(tm, 2, 64));
            tm = fmaxf(tm, __shfl_xor(tm, 4, 64));
            tm = fmaxf(tm, __shfl_xor(tm, 8, 64));
            const float nm = fmaxf(m[i], tm);
            const float alpha = __expf(m[i] - nm);
            float rs = 0.0f;
#pragma unroll
            for (int j = 0; j < 4; ++j) {
                const float p = __expf(s[i][j] - nm);
                s[i][j] = p;
                rs += p;
            }
            rs += __shfl_xor(rs, 1, 64);
            rs += __shfl_xor(rs, 2, 64);
            rs += __shfl_xor(rs, 4, 64);
            rs += __shfl_xor(rs, 8, 64);
            l[i] = l[i] * alpha + rs;
            m[i] = nm;
#pragma unroll
            for (int j = 0; j < 4; ++j) o[i][j] *= alpha;
        }

        __syncthreads();   // everyone done reading K from KP
        // ---- write P into KP as [q][k] ----
#pragma unroll
        for (int i = 0; i < 4; ++i)
            *(float4*)&KP[ty * 4 + i][tx * 4] =
                make_float4(s[i][0], s[i][1], s[i][2], s[i][3]);
        __syncthreads();

        // ---- O += P V (4x4 per thread), kk unrolled by 2 ----
#pragma unroll 4
        for (int kk = 0; kk < 64; kk += 2) {
            const float4 v0 = *(const float4*)&Vs[kk][tx * 4];
            const float4 v1 = *(const float4*)&Vs[kk + 1][tx * 4];
#pragma unroll
            for (int i = 0; i < 4; ++i) {
                const float2 pp = *(const float2*)&KP[ty * 4 + i][kk];
                o[i][0] = fmaf(pp.x, v0.x, fmaf(pp.y, v1.x, o[i][0]));
                o[i][1] = fmaf(pp.x, v0.y, fmaf(pp.y, v1.y, o[i][1]));
                o[i][2] = fmaf(pp.x, v0.z, fmaf(pp.y, v1.z, o[i][2]));
                o[i][3] = fmaf(pp.x, v0.w, fmaf(pp.y, v1.w, o[i][3]));
            }
        }
    }

    // ---- epilogue: O/l -> attn_out (1024, 4096) ----
#pragma unroll
    for (int i = 0; i < 4; ++i) {
        const float inv = 1.0f / l[i];
        const float4 r = make_float4(o[i][0] * inv, o[i][1] * inv,
                                     o[i][2] * inv, o[i][3] * inv);
        *(float4*)&attn_out[(size_t)(qt * 64 + ty * 4 + i) * O_K + n * HD + tx * 4] = r;
    }
}

// ---------------------------------------------------------------------------
extern "C" void kernel_launch(void* const* d_in, const int* in_sizes, int n_in,
                              void* d_out, int out_size, void* d_ws, size_t ws_size,
                              hipStream_t stream) {
    const int*   positions = (const int*)d_in[0];
    const float* hidden    = (const float*)d_in[1];   // (1024, 2880)
    const float* qkv_w     = (const float*)d_in[2];   // (5120, 2880)
    const float* o_w       = (const float*)d_in[3];   // (2880, 4096)
    const float* sinks     = (const float*)d_in[4];   // (64,)
    float* out = (float*)d_out;                       // (1024, 2880)

    float* qkv  = (float*)d_ws;                       // 1024*5120 f32 = 20 MB
    float* attn = qkv + (size_t)S_LEN * QKV_N;        // 1024*4096 f32 = 16 MB

    // 1) qkv = hidden @ qkv_w.T   (M=1024, N=5120, K=2880)
    gemm_bt_f32<<<dim3(QKV_N / TS, S_LEN / TS), 256, 0, stream>>>(
        hidden, qkv_w, qkv, S_LEN, QKV_N, HDIM);

    // 2) RoPE in place on q,k
    rope_kernel<<<S_LEN, 256, 0, stream>>>(qkv, positions);

    // 3) attention -> attn (1024, 4096)
    attn_flash<<<dim3(NH, S_LEN / 64), 256, 0, stream>>>(qkv, sinks, positions, attn);

    // 4) out = attn @ o_w.T   (M=1024, N=2880, K=4096)
    gemm_bt_f32<<<dim3(HDIM / TS, S_LEN / TS), 256, 0, stream>>>(
        attn, o_w, out, S_LEN, HDIM, O_K);
}

// Round 3
// 557.882 us; speedup vs baseline: 6.6840x; 2.4376x over previous
//
#include <hip/hip_runtime.h>
#include <hip/hip_bf16.h>
#include <math.h>

// Problem constants
#define S_LEN 1024
#define HDIM  2880
#define NH    64
#define NKV   8
#define HD    64
#define QKV_N ((NH + 2*NKV) * HD)   // 5120
#define O_K   (NH * HD)             // 4096
#define SCALE 0.125f                // HD^-0.5

typedef __bf16 bf16x8 __attribute__((ext_vector_type(8)));
typedef float  f32x4  __attribute__((ext_vector_type(4)));

__device__ __forceinline__ unsigned short f2bf(float x) {
    union { float f; unsigned u; } v; v.f = x;
    const unsigned r = v.u + 0x7fffu + ((v.u >> 16) & 1u);   // RNE, finite inputs
    return (unsigned short)(r >> 16);
}

// ---------------------------------------------------------------------------
// f32 -> bf16 bulk convert (n multiple of 4)
// ---------------------------------------------------------------------------
__global__ __launch_bounds__(256) void cvt_f32_bf16(const float* __restrict__ src,
                                                    __bf16* __restrict__ dst, int n4) {
    const int stride = gridDim.x * blockDim.x;
    for (int i = blockIdx.x * blockDim.x + threadIdx.x; i < n4; i += stride) {
        const float4 v = ((const float4*)src)[i];
        ushort4 p;
        p.x = f2bf(v.x); p.y = f2bf(v.y); p.z = f2bf(v.z); p.w = f2bf(v.w);
        ((ushort4*)dst)[i] = p;
    }
}

// ---------------------------------------------------------------------------
// MFMA GEMM: C[M,N](f32) = A[M,K](bf16) * B[N,K](f32->bf16 fused)^T
// 128x128 tile, BK=32, 256 threads = 4 waves, each wave owns a 64x64 quadrant
// as a 4x4 grid of 16x16x32 bf16 MFMAs. A staged via global_load_lds (16B),
// B staged with fused f32->bf16 convert. Store predicated on col < N.
// ---------------------------------------------------------------------------
__global__ __launch_bounds__(256) void gemm_bf16_mfma(const __bf16* __restrict__ A,
                                                      const float* __restrict__ B,
                                                      float* __restrict__ C,
                                                      int M, int N, int K) {
    __shared__ __bf16 As[128 * 32];   // [row][k] contiguous, rows of 64 B
    __shared__ __bf16 Bs[128 * 32];

    const int tid  = threadIdx.x;
    const int lane = tid & 63;
    const int wave = tid >> 6;        // 0..3
    const int wr   = wave >> 1;       // row quadrant
    const int wc   = wave & 1;        // col quadrant
    const int row0 = blockIdx.y * 128;
    const int col0 = blockIdx.x * 128;

    const int fr = lane & 15;         // fragment row/col within 16
    const int ks = (lane >> 4) * 8;   // fragment k offset

    f32x4 acc[4][4] = {};

    for (int k0 = 0; k0 < K; k0 += 32) {
        __syncthreads();   // previous frag reads done before overwrite
        // ---- A tile: 128x32 bf16, async direct-to-LDS, 2 chunks/thread ----
#pragma unroll
        for (int it = 0; it < 2; ++it) {
            const int cbase = it * 256 + wave * 64;   // wave-uniform chunk base
            const int ci = cbase + lane;
            const int r  = ci >> 2;                   // 0..127
            const int ch = ci & 3;                    // 16B chunk in row
            const __bf16* gp = A + (size_t)(row0 + r) * K + k0 + ch * 8;
            __builtin_amdgcn_global_load_lds(
                (const __attribute__((address_space(1))) void*)gp,
                (__attribute__((address_space(3))) void*)(As + (size_t)cbase * 8),
                16, 0, 0);
        }
        // ---- B tile: 128x32 f32 -> bf16, 4 float4 chunks/thread ----
#pragma unroll
        for (int it = 0; it < 4; ++it) {
            const int c4 = it * 256 + tid;            // 0..1023
            const int r  = c4 >> 3;                   // 0..127
            const int ch = (c4 & 7) << 2;             // float offset 0..28
            int brow = col0 + r;
            if (brow >= N) brow = N - 1;              // clamp (never stored)
            const float4 bv = *(const float4*)&B[(size_t)brow * K + k0 + ch];
            ushort4 p;
            p.x = f2bf(bv.x); p.y = f2bf(bv.y); p.z = f2bf(bv.z); p.w = f2bf(bv.w);
            *(ushort4*)&Bs[r * 32 + ch] = p;
        }
        __syncthreads();

        // ---- fragments + 16 MFMA ----
        bf16x8 af[4], bfr[4];
#pragma unroll
        for (int mi = 0; mi < 4; ++mi)
            af[mi] = *(const bf16x8*)&As[(wr * 64 + mi * 16 + fr) * 32 + ks];
#pragma unroll
        for (int ni = 0; ni < 4; ++ni)
            bfr[ni] = *(const bf16x8*)&Bs[(wc * 64 + ni * 16 + fr) * 32 + ks];
#pragma unroll
        for (int mi = 0; mi < 4; ++mi)
#pragma unroll
            for (int ni = 0; ni < 4; ++ni)
                acc[mi][ni] = __builtin_amdgcn_mfma_f32_16x16x32_bf16(
                    af[mi], bfr[ni], acc[mi][ni], 0, 0, 0);
    }

    // ---- epilogue: C/D layout col=lane&15, row=(lane>>4)*4+reg ----
#pragma unroll
    for (int ni = 0; ni < 4; ++ni) {
        const int col = col0 + wc * 64 + ni * 16 + fr;
        if (col >= N) continue;
#pragma unroll
        for (int mi = 0; mi < 4; ++mi) {
            const int rbase = row0 + wr * 64 + mi * 16 + (lane >> 4) * 4;
            const f32x4 v = acc[mi][ni];
            C[(size_t)(rbase + 0) * N + col] = v[0];
            C[(size_t)(rbase + 1) * N + col] = v[1];
            C[(size_t)(rbase + 2) * N + col] = v[2];
            C[(size_t)(rbase + 3) * N + col] = v[3];
        }
    }
}

// ---------------------------------------------------------------------------
// RoPE applied in-place to q (heads 0..63) and k (heads 64..71) slices of qkv.
// ---------------------------------------------------------------------------
__global__ __launch_bounds__(256) void rope_kernel(float* __restrict__ qkv,
                                                   const int* __restrict__ positions) {
    const int s = blockIdx.x;
    const float pos = (float)positions[s];
    float* row = qkv + (size_t)s * QKV_N;
    for (int w = threadIdx.x; w < 72 * 32; w += 256) {
        const int h = w >> 5;
        const int t = w & 31;
        const float inv_freq = exp2f(-(float)t * (13.287712379549449f / 32.0f));
        const float ang = pos * inv_freq;
        float sn, cs;
        sincosf(ang, &sn, &cs);
        float* base = row + h * HD;
        const float x1 = base[t];
        const float x2 = base[t + 32];
        base[t]      = x1 * cs - x2 * sn;
        base[t + 32] = x2 * cs + x1 * sn;
    }
}

// ---------------------------------------------------------------------------
// Flash-style attention (unchanged math), output written as bf16 for the
// o-proj MFMA GEMM. One workgroup (256 thr) per (head n, 64-query tile).
// ---------------------------------------------------------------------------
__global__ __launch_bounds__(256) void attn_flash(const float* __restrict__ qkv,
                                                  const float* __restrict__ sinks,
                                                  const int* __restrict__ positions,
                                                  __bf16* __restrict__ attn_out) {
    __shared__ float Qs[64][64];   // [d][q]   (transposed)
    __shared__ float KP[64][64];   // phase 1: K [d][k]; phase 2: P [q][k]
    __shared__ float Vs[64][64];   // [k][d]   (natural)
    __shared__ int   posk[64];

    const int tid = threadIdx.x;
    const int tx  = tid & 15;
    const int ty  = tid >> 4;
    const int n   = blockIdx.x;
    const int qt  = (int)gridDim.y - 1 - (int)blockIdx.y;  // heavy tiles first
    const int g   = n >> 3;

    const float* Qg = qkv + (size_t)(qt * 64) * QKV_N + n * HD;
#pragma unroll
    for (int it = 0; it < 4; ++it) {
        const int flat = it * 256 + tid;
        const int r = flat >> 4, c4 = (flat & 15) * 4;
        const float4 v = *(const float4*)&Qg[(size_t)r * QKV_N + c4];
        Qs[c4 + 0][r] = v.x; Qs[c4 + 1][r] = v.y;
        Qs[c4 + 2][r] = v.z; Qs[c4 + 3][r] = v.w;
    }

    int pq[4];
#pragma unroll
    for (int i = 0; i < 4; ++i) pq[i] = positions[qt * 64 + ty * 4 + i];

    const float sinkv = sinks[n];
    float m[4], l[4], o[4][4];
#pragma unroll
    for (int i = 0; i < 4; ++i) {
        m[i] = sinkv; l[i] = 1.0f;
#pragma unroll
        for (int j = 0; j < 4; ++j) o[i][j] = 0.0f;
    }

    for (int kt = 0; kt <= qt; ++kt) {
        __syncthreads();
        const float* Kg = qkv + (size_t)(kt * 64) * QKV_N + NH * HD + g * HD;
        const float* Vg = Kg + NKV * HD;
#pragma unroll
        for (int it = 0; it < 4; ++it) {
            const int flat = it * 256 + tid;
            const int r = flat >> 4, c4 = (flat & 15) * 4;
            const float4 kv = *(const float4*)&Kg[(size_t)r * QKV_N + c4];
            KP[c4 + 0][r] = kv.x; KP[c4 + 1][r] = kv.y;
            KP[c4 + 2][r] = kv.z; KP[c4 + 3][r] = kv.w;
            const float4 vv = *(const float4*)&Vg[(size_t)r * QKV_N + c4];
            *(float4*)&Vs[r][c4] = vv;
        }
        if (tid < 64) posk[tid] = positions[kt * 64 + tid];
        __syncthreads();

        float s[4][4] = {};
#pragma unroll 4
        for (int d = 0; d < 64; ++d) {
            const float4 qa = *(const float4*)&Qs[d][ty * 4];
            const float4 kb = *(const float4*)&KP[d][tx * 4];
            const float a0 = qa.x, a1 = qa.y, a2 = qa.z, a3 = qa.w;
            const float b0 = kb.x, b1 = kb.y, b2 = kb.z, b3 = kb.w;
            s[0][0] = fmaf(a0, b0, s[0][0]); s[0][1] = fmaf(a0, b1, s[0][1]);
            s[0][2] = fmaf(a0, b2, s[0][2]); s[0][3] = fmaf(a0, b3, s[0][3]);
            s[1][0] = fmaf(a1, b0, s[1][0]); s[1][1] = fmaf(a1, b1, s[1][1]);
            s[1][2] = fmaf(a1, b2, s[1][2]); s[1][3] = fmaf(a1, b3, s[1][3]);
            s[2][0] = fmaf(a2, b0, s[2][0]); s[2][1] = fmaf(a2, b1, s[2][1]);
            s[2][2] = fmaf(a2, b2, s[2][2]); s[2][3] = fmaf(a2, b3, s[2][3]);
            s[3][0] = fmaf(a3, b0, s[3][0]); s[3][1] = fmaf(a3, b1, s[3][1]);
            s[3][2] = fmaf(a3, b2, s[3][2]); s[3][3] = fmaf(a3, b3, s[3][3]);
        }

        const bool diag = (kt == qt);
        int pk[4];
        if (diag) {
#pragma unroll
            for (int j = 0; j < 4; ++j) pk[j] = posk[tx * 4 + j];
        }
#pragma unroll
        for (int i = 0; i < 4; ++i)
#pragma unroll
            for (int j = 0; j < 4; ++j) {
                float sv = s[i][j] * SCALE;
                if (diag && pk[j] > pq[i]) sv = -3.0e38f;
                s[i][j] = sv;
            }

#pragma unroll
        for (int i = 0; i < 4; ++i) {
            float tm = fmaxf(fmaxf(s[i][0], s[i][1]), fmaxf(s[i][2], s[i][3]));
            tm = fmaxf(tm, __shfl_xor(tm, 1, 64));
            tm = fmaxf(tm, __shfl_xor(tm, 2, 64));
            tm = fmaxf(tm, __shfl_xor(tm, 4, 64));
            tm = fmaxf(tm, __shfl_xor(tm, 8, 64));
            const float nm = fmaxf(m[i], tm);
            const float alpha = __expf(m[i] - nm);
            float rs = 0.0f;
#pragma unroll
            for (int j = 0; j < 4; ++j) {
                const float p = __expf(s[i][j] - nm);
                s[i][j] = p;
                rs += p;
            }
            rs += __shfl_xor(rs, 1, 64);
            rs += __shfl_xor(rs, 2, 64);
            rs += __shfl_xor(rs, 4, 64);
            rs += __shfl_xor(rs, 8, 64);
            l[i] = l[i] * alpha + rs;
            m[i] = nm;
#pragma unroll
            for (int j = 0; j < 4; ++j) o[i][j] *= alpha;
        }

        __syncthreads();
#pragma unroll
        for (int i = 0; i < 4; ++i)
            *(float4*)&KP[ty * 4 + i][tx * 4] =
                make_float4(s[i][0], s[i][1], s[i][2], s[i][3]);
        __syncthreads();

#pragma unroll 4
        for (int kk = 0; kk < 64; kk += 2) {
            const float4 v0 = *(const float4*)&Vs[kk][tx * 4];
            const float4 v1 = *(const float4*)&Vs[kk + 1][tx * 4];
#pragma unroll
            for (int i = 0; i < 4; ++i) {
                const float2 pp = *(const float2*)&KP[ty * 4 + i][kk];
                o[i][0] = fmaf(pp.x, v0.x, fmaf(pp.y, v1.x, o[i][0]));
                o[i][1] = fmaf(pp.x, v0.y, fmaf(pp.y, v1.y, o[i][1]));
                o[i][2] = fmaf(pp.x, v0.z, fmaf(pp.y, v1.z, o[i][2]));
                o[i][3] = fmaf(pp.x, v0.w, fmaf(pp.y, v1.w, o[i][3]));
            }
        }
    }

#pragma unroll
    for (int i = 0; i < 4; ++i) {
        const float inv = 1.0f / l[i];
        ushort4 p;
        p.x = f2bf(o[i][0] * inv); p.y = f2bf(o[i][1] * inv);
        p.z = f2bf(o[i][2] * inv); p.w = f2bf(o[i][3] * inv);
        *(ushort4*)&attn_out[(size_t)(qt * 64 + ty * 4 + i) * O_K + n * HD + tx * 4] = p;
    }
}

// ---------------------------------------------------------------------------
extern "C" void kernel_launch(void* const* d_in, const int* in_sizes, int n_in,
                              void* d_out, int out_size, void* d_ws, size_t ws_size,
                              hipStream_t stream) {
    const int*   positions = (const int*)d_in[0];
    const float* hidden    = (const float*)d_in[1];   // (1024, 2880)
    const float* qkv_w     = (const float*)d_in[2];   // (5120, 2880)
    const float* o_w       = (const float*)d_in[3];   // (2880, 4096)
    const float* sinks     = (const float*)d_in[4];   // (64,)
    float* out = (float*)d_out;                       // (1024, 2880)

    // workspace: qkv f32 (20 MB) | attn bf16 (8 MB) | hidden bf16 (5.6 MB)
    float*  qkv     = (float*)d_ws;
    __bf16* attn_bf = (__bf16*)(qkv + (size_t)S_LEN * QKV_N);
    __bf16* hid_bf  = attn_bf + (size_t)S_LEN * O_K;

    // 0) hidden f32 -> bf16
    cvt_f32_bf16<<<512, 256, 0, stream>>>(hidden, hid_bf, S_LEN * HDIM / 4);

    // 1) qkv = hidden @ qkv_w.T   (M=1024, N=5120, K=2880)
    gemm_bf16_mfma<<<dim3(QKV_N / 128, S_LEN / 128), 256, 0, stream>>>(
        hid_bf, qkv_w, qkv, S_LEN, QKV_N, HDIM);

    // 2) RoPE in place on q,k
    rope_kernel<<<S_LEN, 256, 0, stream>>>(qkv, positions);

    // 3) attention -> attn_bf (1024, 4096) bf16
    attn_flash<<<dim3(NH, S_LEN / 64), 256, 0, stream>>>(qkv, sinks, positions, attn_bf);

    // 4) out = attn @ o_w.T   (M=1024, N=2880, K=4096), N not /128 -> 23 tiles
    gemm_bf16_mfma<<<dim3((HDIM + 127) / 128, S_LEN / 128), 256, 0, stream>>>(
        attn_bf, o_w, out, S_LEN, HDIM, O_K);
}

// Round 4
// 356.259 us; speedup vs baseline: 10.4668x; 1.5659x over previous
//
#include <hip/hip_runtime.h>
#include <hip/hip_bf16.h>
#include <math.h>

// Problem constants
#define S_LEN 1024
#define HDIM  2880
#define NH    64
#define NKV   8
#define HD    64
#define QKV_N ((NH + 2*NKV) * HD)   // 5120
#define O_K   (NH * HD)             // 4096
#define SCALE 0.125f                // HD^-0.5

typedef _Float16 f16x8 __attribute__((ext_vector_type(8)));
typedef _Float16 f16x4 __attribute__((ext_vector_type(4)));
typedef float    f32x4 __attribute__((ext_vector_type(4)));

// ---------------------------------------------------------------------------
// f32 -> f16 bulk convert (n4 = count of float4 groups)
// ---------------------------------------------------------------------------
__global__ __launch_bounds__(256) void cvt_f32_f16(const float* __restrict__ src,
                                                   _Float16* __restrict__ dst, int n4) {
    const int stride = gridDim.x * blockDim.x;
    for (int i = blockIdx.x * blockDim.x + threadIdx.x; i < n4; i += stride) {
        const float4 v = ((const float4*)src)[i];
        f16x4 p;
        p[0] = (_Float16)v.x; p[1] = (_Float16)v.y;
        p[2] = (_Float16)v.z; p[3] = (_Float16)v.w;
        ((f16x4*)dst)[i] = p;
    }
}

// ---------------------------------------------------------------------------
// MFMA GEMM: C[M,N] = A[M,K](f16) * B[N,K]^T
// 128x128 tile, BK=32, 256 threads = 4 waves, each wave a 64x64 quadrant of
// 4x4 16x16x32 f16 MFMAs. A staged via global_load_lds (16B). B either f16
// via global_load_lds (fast path) or f32 with fused convert (fallback).
// ---------------------------------------------------------------------------
template<bool B_F32, typename CT>
__global__ __launch_bounds__(256) void gemm_f16(const _Float16* __restrict__ A,
                                                const void* __restrict__ Bp,
                                                CT* __restrict__ C,
                                                int M, int N, int K) {
    __shared__ __align__(16) _Float16 As[128 * 32];
    __shared__ __align__(16) _Float16 Bs[128 * 32];

    const int tid  = threadIdx.x;
    const int lane = tid & 63;
    const int wave = tid >> 6;
    const int wr   = wave >> 1;
    const int wc   = wave & 1;
    const int row0 = blockIdx.y * 128;
    const int col0 = blockIdx.x * 128;

    const int fr = lane & 15;
    const int ks = (lane >> 4) * 8;

    f32x4 acc[4][4] = {};

    for (int k0 = 0; k0 < K; k0 += 32) {
        __syncthreads();
        // ---- A tile: 128x32 f16, async direct-to-LDS ----
#pragma unroll
        for (int it = 0; it < 2; ++it) {
            const int cbase = it * 256 + wave * 64;
            const int ci = cbase + lane;
            const int r  = ci >> 2;
            const int ch = ci & 3;
            const _Float16* gp = A + (size_t)(row0 + r) * K + k0 + ch * 8;
            __builtin_amdgcn_global_load_lds(
                (const __attribute__((address_space(1))) void*)gp,
                (__attribute__((address_space(3))) void*)(As + (size_t)cbase * 8),
                16, 0, 0);
        }
        if constexpr (B_F32) {
            const float* B = (const float*)Bp;
#pragma unroll
            for (int it = 0; it < 4; ++it) {
                const int c4 = it * 256 + tid;
                const int r  = c4 >> 3;
                const int ch = (c4 & 7) << 2;
                int brow = col0 + r;
                if (brow >= N) brow = N - 1;
                const float4 bv = *(const float4*)&B[(size_t)brow * K + k0 + ch];
                f16x4 p;
                p[0] = (_Float16)bv.x; p[1] = (_Float16)bv.y;
                p[2] = (_Float16)bv.z; p[3] = (_Float16)bv.w;
                *(f16x4*)&Bs[r * 32 + ch] = p;
            }
        } else {
            const _Float16* B = (const _Float16*)Bp;
#pragma unroll
            for (int it = 0; it < 2; ++it) {
                const int cbase = it * 256 + wave * 64;
                const int ci = cbase + lane;
                const int r  = ci >> 2;
                const int ch = ci & 3;
                int brow = col0 + r;
                if (brow >= N) brow = N - 1;   // rows past N never stored
                const _Float16* gp = B + (size_t)brow * K + k0 + ch * 8;
                __builtin_amdgcn_global_load_lds(
                    (const __attribute__((address_space(1))) void*)gp,
                    (__attribute__((address_space(3))) void*)(Bs + (size_t)cbase * 8),
                    16, 0, 0);
            }
        }
        __syncthreads();

        f16x8 af[4], bfr[4];
#pragma unroll
        for (int mi = 0; mi < 4; ++mi)
            af[mi] = *(const f16x8*)&As[(wr * 64 + mi * 16 + fr) * 32 + ks];
#pragma unroll
        for (int ni = 0; ni < 4; ++ni)
            bfr[ni] = *(const f16x8*)&Bs[(wc * 64 + ni * 16 + fr) * 32 + ks];
#pragma unroll
        for (int mi = 0; mi < 4; ++mi)
#pragma unroll
            for (int ni = 0; ni < 4; ++ni)
                acc[mi][ni] = __builtin_amdgcn_mfma_f32_16x16x32_f16(
                    af[mi], bfr[ni], acc[mi][ni], 0, 0, 0);
    }

    // C/D layout: col = lane&15, row = (lane>>4)*4 + reg
#pragma unroll
    for (int ni = 0; ni < 4; ++ni) {
        const int col = col0 + wc * 64 + ni * 16 + fr;
        if (col >= N) continue;
#pragma unroll
        for (int mi = 0; mi < 4; ++mi) {
            const int rbase = row0 + wr * 64 + mi * 16 + (lane >> 4) * 4;
            const f32x4 v = acc[mi][ni];
            C[(size_t)(rbase + 0) * N + col] = (CT)v[0];
            C[(size_t)(rbase + 1) * N + col] = (CT)v[1];
            C[(size_t)(rbase + 2) * N + col] = (CT)v[2];
            C[(size_t)(rbase + 3) * N + col] = (CT)v[3];
        }
    }
}

// ---------------------------------------------------------------------------
// RoPE in-place on f16 qkv: q heads 0..63, k heads 64..71.
// ---------------------------------------------------------------------------
__global__ __launch_bounds__(256) void rope_kernel(_Float16* __restrict__ qkv,
                                                   const int* __restrict__ positions) {
    const int s = blockIdx.x;
    const float pos = (float)positions[s];
    _Float16* row = qkv + (size_t)s * QKV_N;
    for (int w = threadIdx.x; w < 72 * 32; w += 256) {
        const int h = w >> 5;
        const int t = w & 31;
        const float inv_freq = exp2f(-(float)t * (13.287712379549449f / 32.0f));
        const float ang = pos * inv_freq;
        float sn, cs;
        sincosf(ang, &sn, &cs);
        _Float16* base = row + h * HD;
        const float x1 = (float)base[t];
        const float x2 = (float)base[t + 32];
        base[t]      = (_Float16)(x1 * cs - x2 * sn);
        base[t + 32] = (_Float16)(x2 * cs + x1 * sn);
    }
}

// ---------------------------------------------------------------------------
// MFMA flash attention. Block = 256 thr = 4 waves, per (head n, 64-q tile).
// Wave w owns S/O rows [16w,16w+16). Q A-frags direct from global (regs).
// K staged [kk][d] (B-frag for QK^T); V staged transposed [d][kk] (B-frag for
// PV). P goes through a wave-private LDS tile (no barrier needed).
// Row stride 72 f16 (144 B) keeps 16B alignment for ds_read_b128.
// ---------------------------------------------------------------------------
#define LSTR 72
__global__ __launch_bounds__(256) void attn_mfma(const _Float16* __restrict__ qkv,
                                                 const float* __restrict__ sinks,
                                                 const int* __restrict__ positions,
                                                 _Float16* __restrict__ attn_out) {
    __shared__ __align__(16) _Float16 Ks[64 * LSTR];
    __shared__ __align__(16) _Float16 Vt[64 * LSTR];
    __shared__ __align__(16) _Float16 Ps[64 * LSTR];
    __shared__ int posk[64];

    const int tid  = threadIdx.x;
    const int lane = tid & 63;
    const int wave = tid >> 6;
    const int fr   = lane & 15;
    const int quad = lane >> 4;
    const int ks8  = quad * 8;
    const int n    = blockIdx.x;
    const int qt   = (int)gridDim.y - 1 - (int)blockIdx.y;   // heavy tiles first
    const int g    = n >> 3;

    // Q A-frags straight from global (roped f16 qkv), held in regs
    const _Float16* qrow = qkv + (size_t)(qt * 64 + wave * 16 + fr) * QKV_N + n * HD;
    const f16x8 a_q0 = *(const f16x8*)&qrow[ks8];
    const f16x8 a_q1 = *(const f16x8*)&qrow[32 + ks8];

    int pq[4];
#pragma unroll
    for (int r = 0; r < 4; ++r)
        pq[r] = positions[qt * 64 + wave * 16 + quad * 4 + r];

    const float sinkv = sinks[n];
    float m[4], l[4];
    f32x4 o[4] = {};
#pragma unroll
    for (int r = 0; r < 4; ++r) { m[r] = sinkv; l[r] = 1.0f; }

    for (int kt = 0; kt <= qt; ++kt) {
        __syncthreads();   // all waves done reading Ks/Vt of prev iter
        const _Float16* Kg = qkv + (size_t)(kt * 64) * QKV_N + NH * HD + g * HD;
        const _Float16* Vg = Kg + NKV * HD;
#pragma unroll
        for (int it = 0; it < 2; ++it) {
            const int c = tid * 2 + it;          // 0..511 chunks of 8 f16
            const int r = c >> 3, off8 = (c & 7) * 8;
            const f16x8 kv = *(const f16x8*)&Kg[(size_t)r * QKV_N + off8];
            *(f16x8*)&Ks[r * LSTR + off8] = kv;
            const f16x8 vv = *(const f16x8*)&Vg[(size_t)r * QKV_N + off8];
#pragma unroll
            for (int j = 0; j < 8; ++j) Vt[(off8 + j) * LSTR + r] = vv[j];
        }
        if (tid < 64) posk[tid] = positions[kt * 64 + tid];
        __syncthreads();

        // ---- S = Q K^T : rows 16w..16w+15, all 64 cols ----
        f32x4 s[4] = {};
#pragma unroll
        for (int nt = 0; nt < 4; ++nt) {
            const f16x8 b0 = *(const f16x8*)&Ks[(nt * 16 + fr) * LSTR + ks8];
            s[nt] = __builtin_amdgcn_mfma_f32_16x16x32_f16(a_q0, b0, s[nt], 0, 0, 0);
            const f16x8 b1 = *(const f16x8*)&Ks[(nt * 16 + fr) * LSTR + 32 + ks8];
            s[nt] = __builtin_amdgcn_mfma_f32_16x16x32_f16(a_q1, b1, s[nt], 0, 0, 0);
        }

        // ---- scale + causal mask (diag tile only) ----
        const bool diag = (kt == qt);
        int pk[4];
        if (diag) {
#pragma unroll
            for (int nt = 0; nt < 4; ++nt) pk[nt] = posk[nt * 16 + fr];
        }
#pragma unroll
        for (int nt = 0; nt < 4; ++nt)
#pragma unroll
            for (int r = 0; r < 4; ++r) {
                float sv = s[nt][r] * SCALE;
                if (diag && pk[nt] > pq[r]) sv = -3.0e38f;
                s[nt][r] = sv;
            }

        // ---- online softmax per row (reduce over the 16 fr-lanes) ----
#pragma unroll
        for (int r = 0; r < 4; ++r) {
            float tm = fmaxf(fmaxf(s[0][r], s[1][r]), fmaxf(s[2][r], s[3][r]));
            tm = fmaxf(tm, __shfl_xor(tm, 1, 64));
            tm = fmaxf(tm, __shfl_xor(tm, 2, 64));
            tm = fmaxf(tm, __shfl_xor(tm, 4, 64));
            tm = fmaxf(tm, __shfl_xor(tm, 8, 64));
            const float nm = fmaxf(m[r], tm);
            const float alpha = __expf(m[r] - nm);
            float rs = 0.0f;
#pragma unroll
            for (int nt = 0; nt < 4; ++nt) {
                const float p = __expf(s[nt][r] - nm);
                s[nt][r] = p;
                rs += p;
            }
            rs += __shfl_xor(rs, 1, 64);
            rs += __shfl_xor(rs, 2, 64);
            rs += __shfl_xor(rs, 4, 64);
            rs += __shfl_xor(rs, 8, 64);
            l[r] = l[r] * alpha + rs;
            m[r] = nm;
#pragma unroll
            for (int nt = 0; nt < 4; ++nt) o[nt][r] *= alpha;
        }

        // ---- P -> wave-private LDS rows [16w,16w+16) ----
#pragma unroll
        for (int nt = 0; nt < 4; ++nt)
#pragma unroll
            for (int r = 0; r < 4; ++r)
                Ps[(wave * 16 + quad * 4 + r) * LSTR + nt * 16 + fr] = (_Float16)s[nt][r];
        __threadfence_block();   // order ds_write -> ds_read (same wave)

        // ---- O += P V ----
#pragma unroll
        for (int k2 = 0; k2 < 2; ++k2) {
            const f16x8 ap = *(const f16x8*)&Ps[(wave * 16 + fr) * LSTR + k2 * 32 + ks8];
#pragma unroll
            for (int nt = 0; nt < 4; ++nt) {
                const f16x8 bv = *(const f16x8*)&Vt[(nt * 16 + fr) * LSTR + k2 * 32 + ks8];
                o[nt] = __builtin_amdgcn_mfma_f32_16x16x32_f16(ap, bv, o[nt], 0, 0, 0);
            }
        }
    }

    // ---- epilogue: O/l -> attn_out f16 (1024, 4096) ----
#pragma unroll
    for (int r = 0; r < 4; ++r) {
        const float inv = 1.0f / l[r];
        const size_t row = (size_t)(qt * 64 + wave * 16 + quad * 4 + r);
#pragma unroll
        for (int nt = 0; nt < 4; ++nt)
            attn_out[row * O_K + n * HD + nt * 16 + fr] = (_Float16)(o[nt][r] * inv);
    }
}

// ---------------------------------------------------------------------------
extern "C" void kernel_launch(void* const* d_in, const int* in_sizes, int n_in,
                              void* d_out, int out_size, void* d_ws, size_t ws_size,
                              hipStream_t stream) {
    const int*   positions = (const int*)d_in[0];
    const float* hidden    = (const float*)d_in[1];   // (1024, 2880)
    const float* qkv_w     = (const float*)d_in[2];   // (5120, 2880)
    const float* o_w       = (const float*)d_in[3];   // (2880, 4096)
    const float* sinks     = (const float*)d_in[4];   // (64,)
    float* out = (float*)d_out;                       // (1024, 2880)

    const size_t n_qkvw = (size_t)QKV_N * HDIM;       // 14,745,600
    const size_t n_ow   = (size_t)HDIM * O_K;         // 11,796,480
    const size_t n_hid  = (size_t)S_LEN * HDIM;       //  2,949,120
    const size_t n_qkv  = (size_t)S_LEN * QKV_N;      // 10,485,760 elems? no: 5,242,880
    const size_t n_attn = (size_t)S_LEN * O_K;        //  4,194,304

    const size_t need_fast = (n_qkvw + n_ow + n_hid + n_qkv + n_attn) * sizeof(_Float16);
    const bool fast = ws_size >= need_fast;

    if (fast) {
        _Float16* qkv_w_h = (_Float16*)d_ws;
        _Float16* o_w_h   = qkv_w_h + n_qkvw;
        _Float16* hid_h   = o_w_h + n_ow;        // also OOB slack for o_w_h tail
        _Float16* qkv_h   = hid_h + n_hid;
        _Float16* attn_h  = qkv_h + n_qkv;

        cvt_f32_f16<<<2048, 256, 0, stream>>>(hidden, hid_h, (int)(n_hid / 4));
        cvt_f32_f16<<<2048, 256, 0, stream>>>(qkv_w, qkv_w_h, (int)(n_qkvw / 4));
        cvt_f32_f16<<<2048, 256, 0, stream>>>(o_w, o_w_h, (int)(n_ow / 4));

        gemm_f16<false, _Float16><<<dim3(QKV_N / 128, S_LEN / 128), 256, 0, stream>>>(
            hid_h, qkv_w_h, qkv_h, S_LEN, QKV_N, HDIM);
        rope_kernel<<<S_LEN, 256, 0, stream>>>(qkv_h, positions);
        attn_mfma<<<dim3(NH, S_LEN / 64), 256, 0, stream>>>(qkv_h, sinks, positions, attn_h);
        gemm_f16<false, float><<<dim3((HDIM + 127) / 128, S_LEN / 128), 256, 0, stream>>>(
            attn_h, o_w_h, out, S_LEN, HDIM, O_K);
    } else {
        _Float16* hid_h  = (_Float16*)d_ws;
        _Float16* qkv_h  = hid_h + n_hid;
        _Float16* attn_h = qkv_h + n_qkv;

        cvt_f32_f16<<<2048, 256, 0, stream>>>(hidden, hid_h, (int)(n_hid / 4));
        gemm_f16<true, _Float16><<<dim3(QKV_N / 128, S_LEN / 128), 256, 0, stream>>>(
            hid_h, qkv_w, qkv_h, S_LEN, QKV_N, HDIM);
        rope_kernel<<<S_LEN, 256, 0, stream>>>(qkv_h, positions);
        attn_mfma<<<dim3(NH, S_LEN / 64), 256, 0, stream>>>(qkv_h, sinks, positions, attn_h);
        gemm_f16<true, float><<<dim3((HDIM + 127) / 128, S_LEN / 128), 256, 0, stream>>>(
            attn_h, o_w, out, S_LEN, HDIM, O_K);
    }
}

// Round 5
// 305.774 us; speedup vs baseline: 12.1949x; 1.1651x over previous
//
#include <hip/hip_runtime.h>
#include <hip/hip_bf16.h>
#include <math.h>

// Problem constants
#define S_LEN 1024
#define HDIM  2880
#define NH    64
#define NKV   8
#define HD    64
#define QKV_N ((NH + 2*NKV) * HD)   // 5120
#define O_K   (NH * HD)             // 4096
#define SCALE 0.125f                // HD^-0.5

typedef _Float16 f16x8 __attribute__((ext_vector_type(8)));
typedef _Float16 f16x4 __attribute__((ext_vector_type(4)));
typedef float    f32x4 __attribute__((ext_vector_type(4)));

// ---------------------------------------------------------------------------
// Fused f32 -> f16 convert of up to three arrays (n*4 = element counts)
// ---------------------------------------------------------------------------
__global__ __launch_bounds__(256) void cvt3_f32_f16(
    const float* __restrict__ a, _Float16* __restrict__ da, int na4,
    const float* __restrict__ b, _Float16* __restrict__ db, int nb4,
    const float* __restrict__ c, _Float16* __restrict__ dc, int nc4) {
    const int stride = gridDim.x * blockDim.x;
    const int tot = na4 + nb4 + nc4;
    for (int i = blockIdx.x * blockDim.x + threadIdx.x; i < tot; i += stride) {
        const float* s; _Float16* d; int j = i;
        if (j < na4)            { s = a; d = da; }
        else if (j < na4 + nb4) { j -= na4; s = b; d = db; }
        else                    { j -= na4 + nb4; s = c; d = dc; }
        const float4 v = ((const float4*)s)[j];
        f16x4 p;
        p[0] = (_Float16)v.x; p[1] = (_Float16)v.y;
        p[2] = (_Float16)v.z; p[3] = (_Float16)v.w;
        ((f16x4*)d)[j] = p;
    }
}

// ---------------------------------------------------------------------------
// Split-K MFMA GEMM: Cpart[z][M,N] = A[M,K=(z slice)](f16) * B[N,K]^T
// 128x128 tile, BK=32, 256 threads = 4 waves, each wave a 64x64 quadrant of
// 4x4 16x16x32 f16 MFMAs. grid.z = K-splits; each split writes its own
// partial plane (CT = f16 partial, or f32 when splits==1 for direct output).
// ---------------------------------------------------------------------------
template<bool B_F32, typename CT>
__global__ __launch_bounds__(256) void gemm_f16(const _Float16* __restrict__ A,
                                                const void* __restrict__ Bp,
                                                CT* __restrict__ C,
                                                int M, int N, int K) {
    __shared__ __align__(16) _Float16 As[128 * 32];
    __shared__ __align__(16) _Float16 Bs[128 * 32];

    const int tid  = threadIdx.x;
    const int lane = tid & 63;
    const int wave = tid >> 6;
    const int wr   = wave >> 1;
    const int wc   = wave & 1;
    const int row0 = blockIdx.y * 128;
    const int col0 = blockIdx.x * 128;

    const int klen = K / (int)gridDim.z;
    const int kb   = (int)blockIdx.z * klen;
    CT* Cp = C + (size_t)blockIdx.z * M * N;

    const int fr = lane & 15;
    const int ks = (lane >> 4) * 8;

    f32x4 acc[4][4] = {};

    for (int k0 = kb; k0 < kb + klen; k0 += 32) {
        __syncthreads();
        // ---- A tile: 128x32 f16, async direct-to-LDS ----
#pragma unroll
        for (int it = 0; it < 2; ++it) {
            const int cbase = it * 256 + wave * 64;
            const int ci = cbase + lane;
            const int r  = ci >> 2;
            const int ch = ci & 3;
            const _Float16* gp = A + (size_t)(row0 + r) * K + k0 + ch * 8;
            __builtin_amdgcn_global_load_lds(
                (const __attribute__((address_space(1))) void*)gp,
                (__attribute__((address_space(3))) void*)(As + (size_t)cbase * 8),
                16, 0, 0);
        }
        if constexpr (B_F32) {
            const float* B = (const float*)Bp;
#pragma unroll
            for (int it = 0; it < 4; ++it) {
                const int c4 = it * 256 + tid;
                const int r  = c4 >> 3;
                const int ch = (c4 & 7) << 2;
                int brow = col0 + r;
                if (brow >= N) brow = N - 1;
                const float4 bv = *(const float4*)&B[(size_t)brow * K + k0 + ch];
                f16x4 p;
                p[0] = (_Float16)bv.x; p[1] = (_Float16)bv.y;
                p[2] = (_Float16)bv.z; p[3] = (_Float16)bv.w;
                *(f16x4*)&Bs[r * 32 + ch] = p;
            }
        } else {
            const _Float16* B = (const _Float16*)Bp;
#pragma unroll
            for (int it = 0; it < 2; ++it) {
                const int cbase = it * 256 + wave * 64;
                const int ci = cbase + lane;
                const int r  = ci >> 2;
                const int ch = ci & 3;
                int brow = col0 + r;
                if (brow >= N) brow = N - 1;   // rows past N never stored
                const _Float16* gp = B + (size_t)brow * K + k0 + ch * 8;
                __builtin_amdgcn_global_load_lds(
                    (const __attribute__((address_space(1))) void*)gp,
                    (__attribute__((address_space(3))) void*)(Bs + (size_t)cbase * 8),
                    16, 0, 0);
            }
        }
        __syncthreads();

        f16x8 af[4], bfr[4];
#pragma unroll
        for (int mi = 0; mi < 4; ++mi)
            af[mi] = *(const f16x8*)&As[(wr * 64 + mi * 16 + fr) * 32 + ks];
#pragma unroll
        for (int ni = 0; ni < 4; ++ni)
            bfr[ni] = *(const f16x8*)&Bs[(wc * 64 + ni * 16 + fr) * 32 + ks];
#pragma unroll
        for (int mi = 0; mi < 4; ++mi)
#pragma unroll
            for (int ni = 0; ni < 4; ++ni)
                acc[mi][ni] = __builtin_amdgcn_mfma_f32_16x16x32_f16(
                    af[mi], bfr[ni], acc[mi][ni], 0, 0, 0);
    }

    // C/D layout: col = lane&15, row = (lane>>4)*4 + reg
#pragma unroll
    for (int ni = 0; ni < 4; ++ni) {
        const int col = col0 + wc * 64 + ni * 16 + fr;
        if (col >= N) continue;
#pragma unroll
        for (int mi = 0; mi < 4; ++mi) {
            const int rbase = row0 + wr * 64 + mi * 16 + (lane >> 4) * 4;
            const f32x4 v = acc[mi][ni];
            Cp[(size_t)(rbase + 0) * N + col] = (CT)v[0];
            Cp[(size_t)(rbase + 1) * N + col] = (CT)v[1];
            Cp[(size_t)(rbase + 2) * N + col] = (CT)v[2];
            Cp[(size_t)(rbase + 3) * N + col] = (CT)v[3];
        }
    }
}

// ---------------------------------------------------------------------------
// Fused: sum nsplit f16 qkv partials -> rope q,k -> write f16 (in-place into
// partial 0) ; also emit V transposed as vt[d 512][s 1024] f16.
// One block per sequence position.
// ---------------------------------------------------------------------------
__global__ __launch_bounds__(256) void rope_reduce(_Float16* __restrict__ parts,
                                                   int nsplit,
                                                   _Float16* __restrict__ vt,
                                                   const int* __restrict__ positions) {
    __shared__ float buf[QKV_N];   // 20 KB
    const int s   = blockIdx.x;
    const int tid = threadIdx.x;
    const size_t PSTR = (size_t)S_LEN * QKV_N;

    for (int c = tid; c < QKV_N / 4; c += 256) {
        float4 a = make_float4(0.f, 0.f, 0.f, 0.f);
        for (int j = 0; j < nsplit; ++j) {
            const f16x4 v = ((const f16x4*)(parts + j * PSTR + (size_t)s * QKV_N))[c];
            a.x += (float)v[0]; a.y += (float)v[1];
            a.z += (float)v[2]; a.w += (float)v[3];
        }
        ((float4*)buf)[c] = a;
    }
    __syncthreads();

    const float pos = (float)positions[s];
    _Float16* orow = parts + (size_t)s * QKV_N;   // write into partial 0
    for (int w = tid; w < 72 * 32; w += 256) {
        const int h = w >> 5;
        const int t = w & 31;
        const float inv_freq = exp2f(-(float)t * (13.287712379549449f / 32.0f));
        const float ang = pos * inv_freq;
        float sn, cs;
        sincosf(ang, &sn, &cs);
        const float x1 = buf[h * 64 + t];
        const float x2 = buf[h * 64 + t + 32];
        orow[h * 64 + t]      = (_Float16)(x1 * cs - x2 * sn);
        orow[h * 64 + t + 32] = (_Float16)(x2 * cs + x1 * sn);
    }
    // V -> vt (transposed), cols 4608..5119
    for (int c = tid; c < NKV * HD; c += 256)
        vt[(size_t)c * S_LEN + s] = (_Float16)buf[(NH + NKV) * HD + c];
}

// ---------------------------------------------------------------------------
// o-proj partial reduce: out(f32) = sum of nsplit f16 partials
// ---------------------------------------------------------------------------
__global__ __launch_bounds__(256) void o_reduce(const _Float16* __restrict__ parts,
                                                float* __restrict__ out,
                                                int n4, int nsplit) {
    const size_t PSTR = (size_t)S_LEN * HDIM;
    const int stride = gridDim.x * blockDim.x;
    for (int i = blockIdx.x * blockDim.x + threadIdx.x; i < n4; i += stride) {
        float4 a = make_float4(0.f, 0.f, 0.f, 0.f);
        for (int j = 0; j < nsplit; ++j) {
            const f16x4 v = ((const f16x4*)(parts + j * PSTR))[i];
            a.x += (float)v[0]; a.y += (float)v[1];
            a.z += (float)v[2]; a.w += (float)v[3];
        }
        ((float4*)out)[i] = a;
    }
}

// ---------------------------------------------------------------------------
// MFMA flash attention. Block = 256 thr = 4 waves, per (head n, 64-q tile).
// Wave w owns S/O rows [16w,16w+16). Q A-frags direct from global (regs).
// K staged [kk][d]; V staged from pre-transposed vt -> [d][kk]; P via
// wave-private LDS tile. Row stride 72 f16 keeps 16B align + bank spread.
// ---------------------------------------------------------------------------
#define LSTR 72
__global__ __launch_bounds__(256) void attn_mfma(const _Float16* __restrict__ qkv,
                                                 const _Float16* __restrict__ vt,
                                                 const float* __restrict__ sinks,
                                                 const int* __restrict__ positions,
                                                 _Float16* __restrict__ attn_out) {
    __shared__ __align__(16) _Float16 Ks[64 * LSTR];
    __shared__ __align__(16) _Float16 Vs[64 * LSTR];
    __shared__ __align__(16) _Float16 Ps[64 * LSTR];
    __shared__ int posk[64];

    const int tid  = threadIdx.x;
    const int lane = tid & 63;
    const int wave = tid >> 6;
    const int fr   = lane & 15;
    const int quad = lane >> 4;
    const int ks8  = quad * 8;
    const int n    = blockIdx.x;
    const int qt   = (int)gridDim.y - 1 - (int)blockIdx.y;   // heavy tiles first
    const int g    = n >> 3;

    const _Float16* qrow = qkv + (size_t)(qt * 64 + wave * 16 + fr) * QKV_N + n * HD;
    const f16x8 a_q0 = *(const f16x8*)&qrow[ks8];
    const f16x8 a_q1 = *(const f16x8*)&qrow[32 + ks8];

    int pq[4];
#pragma unroll
    for (int r = 0; r < 4; ++r)
        pq[r] = positions[qt * 64 + wave * 16 + quad * 4 + r];

    const float sinkv = sinks[n];
    float m[4], l[4];
    f32x4 o[4] = {};
#pragma unroll
    for (int r = 0; r < 4; ++r) { m[r] = sinkv; l[r] = 1.0f; }

    for (int kt = 0; kt <= qt; ++kt) {
        __syncthreads();
        const _Float16* Kg = qkv + (size_t)(kt * 64) * QKV_N + NH * HD + g * HD;
        const _Float16* Vg = vt + (size_t)(g * HD) * S_LEN + kt * 64;
#pragma unroll
        for (int it = 0; it < 2; ++it) {
            const int c = it * 256 + tid;        // 0..511 chunks of 8 f16
            const int r = c >> 3, off8 = (c & 7) * 8;
            const f16x8 kv = *(const f16x8*)&Kg[(size_t)r * QKV_N + off8];
            *(f16x8*)&Ks[r * LSTR + off8] = kv;
            const f16x8 vv = *(const f16x8*)&Vg[(size_t)r * S_LEN + off8];
            *(f16x8*)&Vs[r * LSTR + off8] = vv;   // row r = dim d, col = key
        }
        if (tid < 64) posk[tid] = positions[kt * 64 + tid];
        __syncthreads();

        // ---- S = Q K^T ----
        f32x4 s[4] = {};
#pragma unroll
        for (int nt = 0; nt < 4; ++nt) {
            const f16x8 b0 = *(const f16x8*)&Ks[(nt * 16 + fr) * LSTR + ks8];
            s[nt] = __builtin_amdgcn_mfma_f32_16x16x32_f16(a_q0, b0, s[nt], 0, 0, 0);
            const f16x8 b1 = *(const f16x8*)&Ks[(nt * 16 + fr) * LSTR + 32 + ks8];
            s[nt] = __builtin_amdgcn_mfma_f32_16x16x32_f16(a_q1, b1, s[nt], 0, 0, 0);
        }

        // ---- scale + causal mask (diag tile only) ----
        const bool diag = (kt == qt);
        int pk[4];
        if (diag) {
#pragma unroll
            for (int nt = 0; nt < 4; ++nt) pk[nt] = posk[nt * 16 + fr];
        }
#pragma unroll
        for (int nt = 0; nt < 4; ++nt)
#pragma unroll
            for (int r = 0; r < 4; ++r) {
                float sv = s[nt][r] * SCALE;
                if (diag && pk[nt] > pq[r]) sv = -3.0e38f;
                s[nt][r] = sv;
            }

        // ---- online softmax per row (reduce over 16 fr-lanes) ----
#pragma unroll
        for (int r = 0; r < 4; ++r) {
            float tm = fmaxf(fmaxf(s[0][r], s[1][r]), fmaxf(s[2][r], s[3][r]));
            tm = fmaxf(tm, __shfl_xor(tm, 1, 64));
            tm = fmaxf(tm, __shfl_xor(tm, 2, 64));
            tm = fmaxf(tm, __shfl_xor(tm, 4, 64));
            tm = fmaxf(tm, __shfl_xor(tm, 8, 64));
            const float nm = fmaxf(m[r], tm);
            const float alpha = __expf(m[r] - nm);
            float rs = 0.0f;
#pragma unroll
            for (int nt = 0; nt < 4; ++nt) {
                const float p = __expf(s[nt][r] - nm);
                s[nt][r] = p;
                rs += p;
            }
            rs += __shfl_xor(rs, 1, 64);
            rs += __shfl_xor(rs, 2, 64);
            rs += __shfl_xor(rs, 4, 64);
            rs += __shfl_xor(rs, 8, 64);
            l[r] = l[r] * alpha + rs;
            m[r] = nm;
#pragma unroll
            for (int nt = 0; nt < 4; ++nt) o[nt][r] *= alpha;
        }

        // ---- P -> wave-private LDS rows [16w,16w+16) ----
#pragma unroll
        for (int nt = 0; nt < 4; ++nt)
#pragma unroll
            for (int r = 0; r < 4; ++r)
                Ps[(wave * 16 + quad * 4 + r) * LSTR + nt * 16 + fr] = (_Float16)s[nt][r];
        __threadfence_block();

        // ---- O += P V ----
#pragma unroll
        for (int k2 = 0; k2 < 2; ++k2) {
            const f16x8 ap = *(const f16x8*)&Ps[(wave * 16 + fr) * LSTR + k2 * 32 + ks8];
#pragma unroll
            for (int nt = 0; nt < 4; ++nt) {
                const f16x8 bv = *(const f16x8*)&Vs[(nt * 16 + fr) * LSTR + k2 * 32 + ks8];
                o[nt] = __builtin_amdgcn_mfma_f32_16x16x32_f16(ap, bv, o[nt], 0, 0, 0);
            }
        }
    }

    // ---- epilogue ----
#pragma unroll
    for (int r = 0; r < 4; ++r) {
        const float inv = 1.0f / l[r];
        const size_t row = (size_t)(qt * 64 + wave * 16 + quad * 4 + r);
#pragma unroll
        for (int nt = 0; nt < 4; ++nt)
            attn_out[row * O_K + n * HD + nt * 16 + fr] = (_Float16)(o[nt][r] * inv);
    }
}

// ---------------------------------------------------------------------------
extern "C" void kernel_launch(void* const* d_in, const int* in_sizes, int n_in,
                              void* d_out, int out_size, void* d_ws, size_t ws_size,
                              hipStream_t stream) {
    const int*   positions = (const int*)d_in[0];
    const float* hidden    = (const float*)d_in[1];   // (1024, 2880)
    const float* qkv_w     = (const float*)d_in[2];   // (5120, 2880)
    const float* o_w       = (const float*)d_in[3];   // (2880, 4096)
    const float* sinks     = (const float*)d_in[4];   // (64,)
    float* out = (float*)d_out;                       // (1024, 2880)

    const size_t n_qkvw = (size_t)QKV_N * HDIM;       // 14,745,600
    const size_t n_ow   = (size_t)HDIM * O_K;         // 11,796,480
    const size_t n_hid  = (size_t)S_LEN * HDIM;       //  2,949,120
    const size_t n_qkv  = (size_t)S_LEN * QKV_N;      //  5,242,880
    const size_t n_attn = (size_t)S_LEN * O_K;        //  4,194,304
    const size_t n_vt   = (size_t)NKV * HD * S_LEN;   //    524,288
    const size_t n_out  = (size_t)S_LEN * HDIM;       //  2,949,120

    const int SP_Q = 3;   // 2880/3 = 960 = 30 BK-steps
    const int SP_O = 4;   // 4096/4 = 1024 = 32 BK-steps

    const size_t need1 = (n_qkvw + n_ow + n_hid + SP_Q * n_qkv + n_attn + n_vt) * 2;
    const size_t need2 = (n_hid + SP_Q * n_qkv + n_attn + n_vt + SP_O * n_out) * 2;

    if (ws_size >= need1) {
        // Tier 1: pre-converted f16 weights, full split-K
        _Float16* qkv_w_h = (_Float16*)d_ws;
        _Float16* o_w_h   = qkv_w_h + n_qkvw;
        _Float16* hid_h   = o_w_h + n_ow;
        _Float16* qkvp    = hid_h + n_hid;            // SP_Q planes; p0 = roped qkv
        _Float16* attn_h  = qkvp + SP_Q * n_qkv;
        _Float16* vt      = attn_h + n_attn;
        _Float16* opart   = qkv_w_h;                  // reuse (dead after gemm1)

        cvt3_f32_f16<<<2048, 256, 0, stream>>>(hidden, hid_h, (int)(n_hid / 4),
                                               qkv_w, qkv_w_h, (int)(n_qkvw / 4),
                                               o_w, o_w_h, (int)(n_ow / 4));
        gemm_f16<false, _Float16><<<dim3(QKV_N / 128, S_LEN / 128, SP_Q), 256, 0, stream>>>(
            hid_h, qkv_w_h, qkvp, S_LEN, QKV_N, HDIM);
        rope_reduce<<<S_LEN, 256, 0, stream>>>(qkvp, SP_Q, vt, positions);
        attn_mfma<<<dim3(NH, S_LEN / 64), 256, 0, stream>>>(qkvp, vt, sinks, positions, attn_h);
        gemm_f16<false, _Float16><<<dim3((HDIM + 127) / 128, S_LEN / 128, SP_O), 256, 0, stream>>>(
            attn_h, o_w_h, opart, S_LEN, HDIM, O_K);
        o_reduce<<<1024, 256, 0, stream>>>(opart, out, (int)(n_out / 4), SP_O);
    } else if (ws_size >= need2) {
        // Tier 2: fused f32-B conversion in GEMM, full split-K
        _Float16* hid_h  = (_Float16*)d_ws;
        _Float16* qkvp   = hid_h + n_hid;
        _Float16* attn_h = qkvp + SP_Q * n_qkv;
        _Float16* vt     = attn_h + n_attn;
        _Float16* opart  = vt + n_vt;

        cvt3_f32_f16<<<1024, 256, 0, stream>>>(hidden, hid_h, (int)(n_hid / 4),
                                               nullptr, nullptr, 0, nullptr, nullptr, 0);
        gemm_f16<true, _Float16><<<dim3(QKV_N / 128, S_LEN / 128, SP_Q), 256, 0, stream>>>(
            hid_h, qkv_w, qkvp, S_LEN, QKV_N, HDIM);
        rope_reduce<<<S_LEN, 256, 0, stream>>>(qkvp, SP_Q, vt, positions);
        attn_mfma<<<dim3(NH, S_LEN / 64), 256, 0, stream>>>(qkvp, vt, sinks, positions, attn_h);
        gemm_f16<true, _Float16><<<dim3((HDIM + 127) / 128, S_LEN / 128, SP_O), 256, 0, stream>>>(
            attn_h, o_w, opart, S_LEN, HDIM, O_K);
        o_reduce<<<1024, 256, 0, stream>>>(opart, out, (int)(n_out / 4), SP_O);
    } else {
        // Tier 3: minimal workspace, no split-K
        _Float16* hid_h  = (_Float16*)d_ws;
        _Float16* qkvp   = hid_h + n_hid;
        _Float16* attn_h = qkvp + n_qkv;
        _Float16* vt     = attn_h + n_attn;

        cvt3_f32_f16<<<1024, 256, 0, stream>>>(hidden, hid_h, (int)(n_hid / 4),
                                               nullptr, nullptr, 0, nullptr, nullptr, 0);
        gemm_f16<true, _Float16><<<dim3(QKV_N / 128, S_LEN / 128, 1), 256, 0, stream>>>(
            hid_h, qkv_w, qkvp, S_LEN, QKV_N, HDIM);
        rope_reduce<<<S_LEN, 256, 0, stream>>>(qkvp, 1, vt, positions);
        attn_mfma<<<dim3(NH, S_LEN / 64), 256, 0, stream>>>(qkvp, vt, sinks, positions, attn_h);
        gemm_f16<true, float><<<dim3((HDIM + 127) / 128, S_LEN / 128, 1), 256, 0, stream>>>(
            attn_h, o_w, out, S_LEN, HDIM, O_K);
    }
}